// Round 14
// baseline (1120.621 us; speedup 1.0000x reference)
//
#include <hip/hip_runtime.h>
#include <hip/hip_bf16.h>

#define N_NODES 100000
#define N_EDGES 3200000
#define IN_DIM 20
#define HID 64
#define CAP 96
#define SPILL_CAP 8192
#define SCAN_CHUNK 1024

// ---------------- K0: detect edge_index dtype (int32 vs int64) ----------------
__global__ void k_detect(const unsigned* __restrict__ e, int* __restrict__ flag)
{
    int lane = threadIdx.x; // 64 threads
    unsigned hi = e[2 * lane + 1];
    unsigned long long ballot = __ballot(hi != 0u);
    if (lane == 0) *flag = (ballot == 0ULL) ? 1 : 0; // 1 => int64
}

__device__ __forceinline__ void load_edge(const void* eidx, int i64, int e, int E,
                                          int& s, int& d)
{
    if (i64) {
        const long long* p = (const long long*)eidx;
        s = (int)p[e];
        d = (int)p[(long)E + e];
    } else {
        const int* p = (const int*)eidx;
        s = p[e];
        d = p[(long)E + e];
    }
}

// ---------------- K_bucket: single-pass degree count + bucketed CSR ----------------
// cnt[d] doubles as cursor and final in-degree. Overflow (statistically
// unreachable at CAP=96 for Poisson(32)) handled EXACTLY via spill_agg + list.
__global__ __launch_bounds__(256) void k_bucket(
    const void* __restrict__ eidx, const int* __restrict__ flag,
    int* __restrict__ cnt, int* __restrict__ bucket,
    float* __restrict__ spill_agg, const float* __restrict__ x,
    int* __restrict__ spill_cnt, int* __restrict__ spill_list, int E, int N)
{
    const int i64 = *flag;
    int stride = gridDim.x * blockDim.x;
    for (int e = blockIdx.x * blockDim.x + threadIdx.x; e < E; e += stride) {
        int s, d;
        load_edge(eidx, i64, e, E, s, d);
        if ((unsigned)s >= (unsigned)N || (unsigned)d >= (unsigned)N) continue;
        int pos = atomicAdd(&cnt[d], 1);
        if (pos < CAP) {
            bucket[(long)d * CAP + pos] = s;
        } else {
            const float* xs = x + (long)s * IN_DIM;
            float* sa = spill_agg + (long)d * IN_DIM;
            #pragma unroll
            for (int k = 0; k < IN_DIM; ++k) atomicAdd(&sa[k], xs[k]);
            int sp = atomicAdd(spill_cnt, 1);
            if (sp < SPILL_CAP) { spill_list[2 * sp] = d; spill_list[2 * sp + 1] = s; }
        }
    }
}

__global__ __launch_bounds__(256) void k_deginv_from_cnt(
    const int* __restrict__ cnt, float* __restrict__ deginv, int N)
{
    int i = blockIdx.x * blockDim.x + threadIdx.x;
    if (i < N) {
        int c = cnt[i];
        deginv[i] = (c > 0) ? 1.0f / (float)c : 0.0f;
    }
}

// ---------------- scan (H' tier): blockwise Hillis-Steele ----------------
__global__ __launch_bounds__(SCAN_CHUNK) void k_scan_block(
    const int* __restrict__ cnt, int* __restrict__ offs, int* __restrict__ bsum, int N)
{
    __shared__ int buf[2][SCAN_CHUNK];
    int t = threadIdx.x;
    int gid = blockIdx.x * SCAN_CHUNK + t;
    int v = (gid < N) ? cnt[gid] : 0;
    int cur = 0;
    buf[0][t] = v;
    __syncthreads();
    for (int off = 1; off < SCAN_CHUNK; off <<= 1) {
        int nv = buf[cur][t] + ((t >= off) ? buf[cur][t - off] : 0);
        buf[cur ^ 1][t] = nv;
        cur ^= 1;
        __syncthreads();
    }
    int inc = buf[cur][t];
    if (gid < N) offs[gid] = inc - v;
    if (t == SCAN_CHUNK - 1) bsum[blockIdx.x] = inc;
}

__global__ void k_scan_partials(int* __restrict__ bsum, int nb)
{
    if (threadIdx.x == 0) {
        int run = 0;
        for (int b = 0; b < nb; ++b) { int v = bsum[b]; bsum[b] = run; run += v; }
    }
}

__global__ __launch_bounds__(256) void k_scan_add(
    int* __restrict__ offs, int* __restrict__ cursor, float* __restrict__ deginv,
    const int* __restrict__ cnt, const int* __restrict__ bsum, int N)
{
    int i = blockIdx.x * blockDim.x + threadIdx.x;
    if (i < N) {
        int o = offs[i] + bsum[i >> 10];
        offs[i] = o;
        cursor[i] = o;
        int c = cnt[i];
        deginv[i] = (c > 0) ? 1.0f / (float)c : 0.0f;
    }
}

// ---------------- K_scatter_nw (H' tier): CSR build, no w ----------------
__global__ __launch_bounds__(256) void k_scatter_nw(
    const void* __restrict__ eidx, const int* __restrict__ flag,
    int* __restrict__ cursor, int* __restrict__ csr, int E, int N)
{
    const int i64 = *flag;
    int stride = gridDim.x * blockDim.x;
    for (int e = blockIdx.x * blockDim.x + threadIdx.x; e < E; e += stride) {
        int s, d;
        load_edge(eidx, i64, e, E, s, d);
        if ((unsigned)s >= (unsigned)N || (unsigned)d >= (unsigned)N) continue;
        int pos = atomicAdd(&cursor[d], 1);
        csr[pos] = s;
    }
}

// ---------------- K_fused1: gather-aggregate + layer-1 matvec + S2, writes h ----------------
// cursor_or_null != null  => CSR mode: base = cursor[n]-c, limit = c
// cursor_or_null == null  => bucket mode: base = n*CAP,    limit = min(c,CAP)
__global__ __launch_bounds__(256) void k_fused1(
    const int* __restrict__ cursor_or_null, const int* __restrict__ cnt,
    const int* __restrict__ list, const float* __restrict__ x,
    const float* __restrict__ deginv, const float* __restrict__ spill_agg,
    const float* __restrict__ W1l, const float* __restrict__ b1,
    const float* __restrict__ W1r,
    float* __restrict__ h, float* __restrict__ S2, int N)
{
    __shared__ float sW1l[IN_DIM * HID];
    __shared__ float sW1r[IN_DIM * HID];
    __shared__ float sb1[HID];
    for (int i = threadIdx.x; i < IN_DIM * HID; i += blockDim.x) {
        sW1l[i] = W1l[i];
        sW1r[i] = W1r[i];
    }
    if (threadIdx.x < HID) sb1[threadIdx.x] = b1[threadIdx.x];
    __syncthreads();

    const int lane = threadIdx.x & 63;
    const int wid = (blockIdx.x * blockDim.x + threadIdx.x) >> 6;
    const int wtot = (gridDim.x * blockDim.x) >> 6;
    const int g = lane / 20;
    const int dim = lane % 20;
    const bool active = lane < 60;

    float s2 = 0.0f;
    for (int n = wid; n < N; n += wtot) {
        int c = cnt[n];
        int limit = cursor_or_null ? c : min(c, CAP);
        long base = cursor_or_null ? (long)cursor_or_null[n] - c : (long)n * CAP;
        float v = 0.0f;
        if (active) {
            for (int i = g; i < limit; i += 3) {
                int s = list[base + i];
                v += x[(long)s * IN_DIM + dim];
            }
        }
        float v1 = __shfl(v, lane + 20);
        float v2 = __shfl(v, lane + 40);
        float va = 0.0f;
        if (lane < IN_DIM) va = v + v1 + v2 + spill_agg[(long)n * IN_DIM + lane];
        float xr = 0.0f;
        if (lane >= 32 && lane < 32 + IN_DIM) xr = x[(long)n * IN_DIM + (lane - 32)];
        float di = deginv[n];
        float hh = sb1[lane];
        #pragma unroll
        for (int k = 0; k < IN_DIM; ++k) {
            float ak = __shfl(va, k) * di;
            float xk = __shfl(xr, 32 + k);
            hh += ak * sW1l[k * HID + lane] + xk * sW1r[k * HID + lane];
        }
        hh = fmaxf(hh, 0.0f);
        h[(long)n * HID + lane] = hh;
        s2 += hh;
    }
    atomicAdd(&S2[lane], s2);
}

// ---------------- K_gather2: S1 = sum_d deginv[d] * sum_{s in N(d)} h[s] ----------------
__global__ __launch_bounds__(256) void k_gather2(
    const int* __restrict__ cursor_or_null, const int* __restrict__ cnt,
    const int* __restrict__ list, const float* __restrict__ deginv,
    const float* __restrict__ h, const int* __restrict__ spill_cnt,
    const int* __restrict__ spill_list, float* __restrict__ S1, int N)
{
    const int lane = threadIdx.x & 63;
    const int wid = (blockIdx.x * blockDim.x + threadIdx.x) >> 6;
    const int wtot = (gridDim.x * blockDim.x) >> 6;

    float s1 = 0.0f;
    for (int n = wid; n < N; n += wtot) {
        int c = cnt[n];
        int limit = cursor_or_null ? c : min(c, CAP);
        long base = cursor_or_null ? (long)cursor_or_null[n] - c : (long)n * CAP;
        float hs = 0.0f;
        for (int i = 0; i < limit; ++i) {
            int s = list[base + i];              // wave-uniform broadcast load
            hs += h[(long)s * HID + lane];       // 256B coalesced row
        }
        s1 += deginv[n] * hs;
    }
    if (wid == 0) { // exact spill correction (normally empty)
        int nsp = min(*spill_cnt, SPILL_CAP);
        for (int i = 0; i < nsp; ++i) {
            int d = spill_list[2 * i], s = spill_list[2 * i + 1];
            s1 += deginv[d] * h[(long)s * HID + lane];
        }
    }
    atomicAdd(&S1[lane], s1);
}

// ---------------- K5: final tiny matvec + bias + mean ----------------
__global__ void k_final(const float* __restrict__ S1, const float* __restrict__ S2,
                        const float* __restrict__ W2l, const float* __restrict__ b2,
                        const float* __restrict__ W2r, float* __restrict__ out, float invN)
{
    int j = threadIdx.x; // 64 threads
    float acc1 = 0.0f, acc2 = 0.0f;
    for (int k = 0; k < HID; ++k) {
        acc1 += S1[k] * W2l[k * HID + j];
        acc2 += S2[k] * W2r[k * HID + j];
    }
    out[j] = acc1 * invN + b2[j] + acc2 * invN;
}

// ================= legacy (round-5 proven) path kernels =================
__global__ __launch_bounds__(256) void k_hist(
    const void* __restrict__ eidx, const int* __restrict__ flag,
    int* __restrict__ cnt, int E, int N)
{
    const int i64 = *flag;
    int stride = gridDim.x * blockDim.x;
    for (int e = blockIdx.x * blockDim.x + threadIdx.x; e < E; e += stride) {
        int d;
        if (i64) d = (int)((const long long*)eidx)[(long)E + e];
        else     d = ((const int*)eidx)[(long)E + e];
        if ((unsigned)d < (unsigned)N) atomicAdd(&cnt[d], 1);
    }
}

__global__ __launch_bounds__(256) void k_scatter_w(
    const void* __restrict__ eidx, const int* __restrict__ flag,
    int* __restrict__ cursor, int* __restrict__ csr,
    const float* __restrict__ deginv, float* __restrict__ w, int E, int N)
{
    const int i64 = *flag;
    int stride = gridDim.x * blockDim.x;
    for (int e = blockIdx.x * blockDim.x + threadIdx.x; e < E; e += stride) {
        int s, d;
        load_edge(eidx, i64, e, E, s, d);
        if ((unsigned)s >= (unsigned)N || (unsigned)d >= (unsigned)N) continue;
        int pos = atomicAdd(&cursor[d], 1);
        csr[pos] = s;
        atomicAdd(&w[s], deginv[d]);
    }
}

__global__ __launch_bounds__(256) void k_agg(
    const int* __restrict__ offs, const int* __restrict__ cnt,
    const int* __restrict__ csr, const float* __restrict__ x,
    float* __restrict__ agg1, int N)
{
    const int lane = threadIdx.x & 63;
    const int wid = (blockIdx.x * blockDim.x + threadIdx.x) >> 6;
    const int wtot = (gridDim.x * blockDim.x) >> 6;
    const int g = lane / 20;
    const int dim = lane % 20;
    const bool active = lane < 60;

    for (int n = wid; n < N; n += wtot) {
        int base = offs[n];
        int c = cnt[n];
        float v = 0.0f;
        if (active) {
            for (int i = g; i < c; i += 3) {
                int s = csr[base + i];
                v += x[(long)s * IN_DIM + dim];
            }
        }
        float v1 = __shfl(v, lane + 20);
        float v2 = __shfl(v, lane + 40);
        if (lane < 20) agg1[(long)n * IN_DIM + lane] = v + v1 + v2;
    }
}

__global__ __launch_bounds__(256) void k_node_layer1(
    const float* __restrict__ x, const float* __restrict__ agg1,
    const float* __restrict__ deginv, const float* __restrict__ w,
    const float* __restrict__ W1l, const float* __restrict__ b1,
    const float* __restrict__ W1r,
    float* __restrict__ S1, float* __restrict__ S2, int N)
{
    __shared__ float sW1l[IN_DIM * HID];
    __shared__ float sW1r[IN_DIM * HID];
    __shared__ float sb1[HID];
    for (int i = threadIdx.x; i < IN_DIM * HID; i += blockDim.x) {
        sW1l[i] = W1l[i];
        sW1r[i] = W1r[i];
    }
    if (threadIdx.x < HID) sb1[threadIdx.x] = b1[threadIdx.x];
    __syncthreads();

    const int lane = threadIdx.x & 63;
    const int wave_id = (blockIdx.x * blockDim.x + threadIdx.x) >> 6;
    const int waves_total = (gridDim.x * blockDim.x) >> 6;

    float s1 = 0.0f, s2 = 0.0f;
    for (int n = wave_id; n < N; n += waves_total) {
        float v = 0.0f;
        if (lane < IN_DIM) v = agg1[(long)n * IN_DIM + lane];
        else if (lane >= 32 && lane < 32 + IN_DIM) v = x[(long)n * IN_DIM + (lane - 32)];
        float di = deginv[n];
        float h = sb1[lane];
        #pragma unroll
        for (int k = 0; k < IN_DIM; ++k) {
            float ak = __shfl(v, k) * di;
            float xk = __shfl(v, 32 + k);
            h += ak * sW1l[k * HID + lane];
            h += xk * sW1r[k * HID + lane];
        }
        h = fmaxf(h, 0.0f);
        s2 += h;
        s1 += w[n] * h;
    }
    atomicAdd(&S1[lane], s1);
    atomicAdd(&S2[lane], s2);
}

extern "C" void kernel_launch(void* const* d_in, const int* in_sizes, int n_in,
                              void* d_out, int out_size, void* d_ws, size_t ws_size,
                              hipStream_t stream)
{
    const float* x   = (const float*)d_in[0];
    const void* eidx = (const void*)d_in[1];
    const float* W1l = (const float*)d_in[2];
    const float* b1  = (const float*)d_in[3];
    const float* W1r = (const float*)d_in[4];
    const float* W2l = (const float*)d_in[5];
    const float* b2  = (const float*)d_in[6];
    const float* W2r = (const float*)d_in[7];
    float* out = (float*)d_out;

    const int N = N_NODES;
    const int E = N_EDGES;
    const long NL = N;

    // shared prefix (words): cnt[N] | deginv[N] | spill_agg[20N] | h[64N] | variant@86N
    const size_t tail_words = 64 + 64 + 1 + 1 + 2 * SPILL_CAP + 128;
    const size_t words_H  = 182UL * N + tail_words;          // bucket tier  (~73 MB)
    const size_t words_Hp = 120UL * N + tail_words;          // CSR-no-w tier (~48 MB)

    int*   cnt    = (int*)d_ws;
    float* deginv = (float*)d_ws + NL;
    float* spagg  = (float*)d_ws + 2 * NL;
    float* h      = (float*)d_ws + 22 * NL;

    if (ws_size >= words_H * 4) {
        // ---------------- Tier H: single-pass buckets ----------------
        int* bucket = (int*)d_ws + 86 * NL;
        float* S1   = (float*)d_ws + 182 * NL;
        float* S2   = S1 + HID;
        int* flag   = (int*)(S2 + HID);
        int* spcnt  = flag + 1;
        int* splist = spcnt + 1;

        hipMemsetAsync(d_ws, 0, 22 * (size_t)N * sizeof(int), stream);   // cnt+deginv+spill_agg
        hipMemsetAsync(S1, 0, (2 * HID + 2) * sizeof(float), stream);    // S1,S2,flag,spcnt

        k_detect<<<1, 64, 0, stream>>>((const unsigned*)eidx, flag);
        k_bucket<<<2048, 256, 0, stream>>>(eidx, flag, cnt, bucket, spagg, x, spcnt, splist, E, N);
        k_deginv_from_cnt<<<(N + 255) / 256, 256, 0, stream>>>(cnt, deginv, N);
        k_fused1<<<1024, 256, 0, stream>>>(nullptr, cnt, bucket, x, deginv, spagg,
                                           W1l, b1, W1r, h, S2, N);
        k_gather2<<<1024, 256, 0, stream>>>(nullptr, cnt, bucket, deginv, h, spcnt, splist, S1, N);
        k_final<<<1, HID, 0, stream>>>(S1, S2, W2l, b2, W2r, out, 1.0f / (float)N);
    } else if (ws_size >= words_Hp * 4) {
        // ---------------- Tier H': CSR without w ----------------
        int* csr    = (int*)d_ws + 86 * NL;
        int* offs   = (int*)d_ws + 118 * NL;
        int* cursor = (int*)d_ws + 119 * NL;
        float* S1   = (float*)d_ws + 120 * NL;
        float* S2   = S1 + HID;
        int* flag   = (int*)(S2 + HID);
        int* spcnt  = flag + 1;
        int* splist = spcnt + 1;
        int* bsum   = splist + 2 * SPILL_CAP;

        hipMemsetAsync(d_ws, 0, 22 * (size_t)N * sizeof(int), stream);
        hipMemsetAsync(S1, 0, (2 * HID + 2) * sizeof(float), stream);

        k_detect<<<1, 64, 0, stream>>>((const unsigned*)eidx, flag);
        k_hist<<<2048, 256, 0, stream>>>(eidx, flag, cnt, E, N);
        int nb = (N + SCAN_CHUNK - 1) / SCAN_CHUNK;
        k_scan_block<<<nb, SCAN_CHUNK, 0, stream>>>(cnt, offs, bsum, N);
        k_scan_partials<<<1, 64, 0, stream>>>(bsum, nb);
        k_scan_add<<<(N + 255) / 256, 256, 0, stream>>>(offs, cursor, deginv, cnt, bsum, N);
        k_scatter_nw<<<2048, 256, 0, stream>>>(eidx, flag, cursor, csr, E, N);
        k_fused1<<<1024, 256, 0, stream>>>(cursor, cnt, csr, x, deginv, spagg,
                                           W1l, b1, W1r, h, S2, N);
        k_gather2<<<1024, 256, 0, stream>>>(cursor, cnt, csr, deginv, h, spcnt, splist, S1, N);
        k_final<<<1, HID, 0, stream>>>(S1, S2, W2l, b2, W2r, out, 1.0f / (float)N);
    } else {
        // ---------------- Tier L: proven round-5 path (23 MB) ----------------
        // layout: cnt[N] | w[N] | deginv[N] | offs[N] | cursor[N] | csr[E] | agg1[20N] | tail
        int*   cntL    = (int*)d_ws;
        float* wvec    = (float*)d_ws + NL;
        float* deginvL = (float*)d_ws + 2 * NL;
        int*   offs    = (int*)d_ws + 3 * NL;
        int*   cursor  = (int*)d_ws + 4 * NL;
        int*   csr     = (int*)d_ws + 5 * NL;
        float* agg1    = (float*)d_ws + 5 * NL + E;
        float* S1      = (float*)d_ws + 25 * NL + E;
        float* S2      = S1 + HID;
        int*   flag    = (int*)(S2 + HID);
        int*   bsum    = flag + 1;

        hipMemsetAsync(d_ws, 0, 2 * (size_t)N * sizeof(int), stream);
        hipMemsetAsync(S1, 0, (2 * HID + 1) * sizeof(float), stream);

        k_detect<<<1, 64, 0, stream>>>((const unsigned*)eidx, flag);
        k_hist<<<2048, 256, 0, stream>>>(eidx, flag, cntL, E, N);
        int nb = (N + SCAN_CHUNK - 1) / SCAN_CHUNK;
        k_scan_block<<<nb, SCAN_CHUNK, 0, stream>>>(cntL, offs, bsum, N);
        k_scan_partials<<<1, 64, 0, stream>>>(bsum, nb);
        k_scan_add<<<(N + 255) / 256, 256, 0, stream>>>(offs, cursor, deginvL, cntL, bsum, N);
        k_scatter_w<<<2048, 256, 0, stream>>>(eidx, flag, cursor, csr, deginvL, wvec, E, N);
        k_agg<<<1024, 256, 0, stream>>>(offs, cntL, csr, x, agg1, N);
        k_node_layer1<<<256, 256, 0, stream>>>(x, agg1, deginvL, wvec, W1l, b1, W1r, S1, S2, N);
        k_final<<<1, HID, 0, stream>>>(S1, S2, W2l, b2, W2r, out, 1.0f / (float)N);
    }
}

// Round 17
// 813.671 us; speedup vs baseline: 1.3772x; 1.3772x over previous
//
#include <hip/hip_runtime.h>
#include <hip/hip_bf16.h>

#define N_NODES 100000
#define N_EDGES 3200000
#define IN_DIM 20
#define HID 64
#define CAP 96

// ---------------- K0: detect edge_index dtype (int32 vs int64) ----------------
__global__ void k_detect(const unsigned* __restrict__ e, int* __restrict__ flag)
{
    int lane = threadIdx.x; // 64 threads
    unsigned hi = e[2 * lane + 1];
    unsigned long long ballot = __ballot(hi != 0u);
    if (lane == 0) *flag = (ballot == 0ULL) ? 1 : 0; // 1 => int64
}

__device__ __forceinline__ void load_edge(const void* eidx, int i64, int e, int E,
                                          int& s, int& d)
{
    if (i64) {
        const long long* p = (const long long*)eidx;
        s = (int)p[e];
        d = (int)p[(long)E + e];
    } else {
        const int* p = (const int*)eidx;
        s = p[e];
        d = p[(long)E + e];
    }
}

// ---------------- K_bucket: single-pass degree count + bucketed CSR ----------------
// cnt[d] doubles as cursor and final in-degree. Overflow (P(deg>96) ~ 1e-18 for
// Poisson(32)) handled EXACTLY via spill_agg fp32 atomics (contributes to agg1 only;
// w and S1 are exact regardless since k_edge_w walks all edges independently).
__global__ __launch_bounds__(256) void k_bucket(
    const void* __restrict__ eidx, const int* __restrict__ flag,
    int* __restrict__ cnt, int* __restrict__ bucket,
    float* __restrict__ spill_agg, const float* __restrict__ x, int E, int N)
{
    const int i64 = *flag;
    int stride = gridDim.x * blockDim.x;
    for (int e = blockIdx.x * blockDim.x + threadIdx.x; e < E; e += stride) {
        int s, d;
        load_edge(eidx, i64, e, E, s, d);
        if ((unsigned)s >= (unsigned)N || (unsigned)d >= (unsigned)N) continue;
        int pos = atomicAdd(&cnt[d], 1);
        if (pos < CAP) {
            bucket[(long)d * CAP + pos] = s;
        } else {
            const float* xs = x + (long)s * IN_DIM;
            float* sa = spill_agg + (long)d * IN_DIM;
            #pragma unroll
            for (int k = 0; k < IN_DIM; ++k) atomicAdd(&sa[k], xs[k]);
        }
    }
}

// ---------------- K_edge_w: w[src] += 1/deg[dst] (deg final after k_bucket) ----------------
__global__ __launch_bounds__(256) void k_edge_w(
    const void* __restrict__ eidx, const int* __restrict__ flag,
    const int* __restrict__ cnt, float* __restrict__ w, int E, int N)
{
    const int i64 = *flag;
    int stride = gridDim.x * blockDim.x;
    for (int e = blockIdx.x * blockDim.x + threadIdx.x; e < E; e += stride) {
        int s, d;
        load_edge(eidx, i64, e, E, s, d);
        if ((unsigned)s >= (unsigned)N || (unsigned)d >= (unsigned)N) continue;
        int c = cnt[d]; // >= 1, this edge counted
        atomicAdd(&w[s], 1.0f / (float)c);
    }
}

// ---------------- K_fused1w: gather-agg + layer-1 + S1/S2, nothing materialized ----------------
// lane j (0..63) owns output channel j. Gather groups: g = lane/20, dim = lane%20.
__global__ __launch_bounds__(256) void k_fused1w(
    const int* __restrict__ cnt, const int* __restrict__ bucket,
    const float* __restrict__ x, const float* __restrict__ w,
    const float* __restrict__ spill_agg,
    const float* __restrict__ W1l, const float* __restrict__ b1,
    const float* __restrict__ W1r,
    float* __restrict__ S1, float* __restrict__ S2, int N)
{
    __shared__ float sW1l[IN_DIM * HID];
    __shared__ float sW1r[IN_DIM * HID];
    __shared__ float sb1[HID];
    for (int i = threadIdx.x; i < IN_DIM * HID; i += blockDim.x) {
        sW1l[i] = W1l[i];
        sW1r[i] = W1r[i];
    }
    if (threadIdx.x < HID) sb1[threadIdx.x] = b1[threadIdx.x];
    __syncthreads();

    const int lane = threadIdx.x & 63;
    const int wid = (blockIdx.x * blockDim.x + threadIdx.x) >> 6;
    const int wtot = (gridDim.x * blockDim.x) >> 6;
    const int g = lane / 20;
    const int dim = lane % 20;
    const bool active = lane < 60;

    float s1 = 0.0f, s2 = 0.0f;
    for (int n = wid; n < N; n += wtot) {
        int c = cnt[n];
        int limit = min(c, CAP);
        long base = (long)n * CAP;
        float v = 0.0f;
        if (active) {
            for (int i = g; i < limit; i += 3) {
                int s = bucket[base + i];       // broadcast within 20-lane group
                v += x[(long)s * IN_DIM + dim]; // 80B coalesced per group
            }
        }
        float v1 = __shfl(v, lane + 20);
        float v2 = __shfl(v, lane + 40);
        float va = 0.0f;
        if (lane < IN_DIM) va = v + v1 + v2 + spill_agg[(long)n * IN_DIM + lane];
        float xr = 0.0f;
        if (lane >= 32 && lane < 32 + IN_DIM) xr = x[(long)n * IN_DIM + (lane - 32)];
        float di = (c > 0) ? 1.0f / (float)c : 0.0f;
        float hh = sb1[lane];
        #pragma unroll
        for (int k = 0; k < IN_DIM; ++k) {
            float ak = __shfl(va, k) * di;
            float xk = __shfl(xr, 32 + k);
            hh += ak * sW1l[k * HID + lane] + xk * sW1r[k * HID + lane];
        }
        hh = fmaxf(hh, 0.0f);
        s2 += hh;
        s1 += w[n] * hh;
    }
    atomicAdd(&S1[lane], s1);
    atomicAdd(&S2[lane], s2);
}

// ---------------- K5: final tiny matvec + bias + mean ----------------
__global__ void k_final(const float* __restrict__ S1, const float* __restrict__ S2,
                        const float* __restrict__ W2l, const float* __restrict__ b2,
                        const float* __restrict__ W2r, float* __restrict__ out, float invN)
{
    int j = threadIdx.x; // 64 threads
    float acc1 = 0.0f, acc2 = 0.0f;
    for (int k = 0; k < HID; ++k) {
        acc1 += S1[k] * W2l[k * HID + j];
        acc2 += S2[k] * W2r[k * HID + j];
    }
    out[j] = acc1 * invN + b2[j] + acc2 * invN;
}

extern "C" void kernel_launch(void* const* d_in, const int* in_sizes, int n_in,
                              void* d_out, int out_size, void* d_ws, size_t ws_size,
                              hipStream_t stream)
{
    const float* x   = (const float*)d_in[0];
    const void* eidx = (const void*)d_in[1];
    const float* W1l = (const float*)d_in[2];
    const float* b1  = (const float*)d_in[3];
    const float* W1r = (const float*)d_in[4];
    const float* W2l = (const float*)d_in[5];
    const float* b2  = (const float*)d_in[6];
    const float* W2r = (const float*)d_in[7];
    float* out = (float*)d_out;

    const int N = N_NODES;
    const int E = N_EDGES;
    const long NL = N;

    // layout (4B words): cnt[N] | w[N] | spill_agg[20N] | bucket[96N] | S1[64] S2[64] flag[1]
    // total = 118N + 129 words ~= 47.2 MB (ws >= 73 MB proven by round-14 tier-H run)
    int*   cnt    = (int*)d_ws;
    float* wvec   = (float*)d_ws + NL;
    float* spagg  = (float*)d_ws + 2 * NL;
    int*   bucket = (int*)d_ws + 22 * NL;
    float* S1     = (float*)d_ws + 118 * NL;
    float* S2     = S1 + HID;
    int*   flag   = (int*)(S2 + HID);

    hipMemsetAsync(d_ws, 0, 22 * (size_t)N * sizeof(int), stream);  // cnt + w + spill_agg
    hipMemsetAsync(S1, 0, (2 * HID + 1) * sizeof(float), stream);   // S1, S2, flag

    k_detect<<<1, 64, 0, stream>>>((const unsigned*)eidx, flag);
    k_bucket<<<2048, 256, 0, stream>>>(eidx, flag, cnt, bucket, spagg, x, E, N);
    k_edge_w<<<2048, 256, 0, stream>>>(eidx, flag, cnt, wvec, E, N);
    k_fused1w<<<1024, 256, 0, stream>>>(cnt, bucket, x, wvec, spagg,
                                        W1l, b1, W1r, S1, S2, N);
    k_final<<<1, HID, 0, stream>>>(S1, S2, W2l, b2, W2r, out, 1.0f / (float)N);
}